// Round 2
// baseline (358.281 us; speedup 1.0000x reference)
//
#include <hip/hip_runtime.h>

// Problem constants (n = 8192 fixed by setup_inputs).
constexpr int NN   = 8192;
constexpr int ROWS = 32;              // rows per block tile
constexpr int COLS = 1024;            // cols per block tile (256 threads * 4)
constexpr int NBLK = (NN / ROWS) * (NN / COLS);   // 256 * 8 = 2048 blocks
constexpr int COPYBLKS = (NN * 3) / 256;          // 96 blocks copy pred_pos

// ce = -mean( Q*log(P) + (1-Q)*log1p(-P) ),  Q = 1/(1+max(d2,0)),
// d2_ij = sq_i + sq_j - 2*dot(y_i, y_j).
// Accumulate in log2 units; scale by ln2 in the final atomic.

__global__ __launch_bounds__(256, 4)
void bce_tsne_kernel(const float* __restrict__ Pstar,
                     const float* __restrict__ pos,
                     float* __restrict__ out)
{
    __shared__ float4 rowC[ROWS];   // {sq_i, -2*y0, -2*y1, -2*y2}
    __shared__ float  waveSum[4];

    const int tid = threadIdx.x;
    const int bid = blockIdx.x;
    const int rowBase = (bid >> 3) * ROWS;    // NN/COLS == 8 col tiles
    const int colBase = (bid & 7) * COLS;

    // Stage row coefficients for this tile's 32 rows into LDS.
    if (tid < ROWS) {
        const int i = rowBase + tid;
        const float y0 = pos[i * 3 + 0];
        const float y1 = pos[i * 3 + 1];
        const float y2 = pos[i * 3 + 2];
        rowC[tid] = make_float4(fmaf(y0, y0, fmaf(y1, y1, y2 * y2)),
                                -2.0f * y0, -2.0f * y1, -2.0f * y2);
    }

    // Each thread owns 4 consecutive columns j0..j0+3 for the whole tile;
    // their y components live in registers (12 contiguous floats = 3 float4).
    const int j0 = colBase + tid * 4;
    const float4 f0 = *(const float4*)(pos + (size_t)j0 * 3);
    const float4 f1 = *(const float4*)(pos + (size_t)j0 * 3 + 4);
    const float4 f2 = *(const float4*)(pos + (size_t)j0 * 3 + 8);
    float ya[4] = {f0.x, f0.w, f1.z, f2.y};
    float yb[4] = {f0.y, f1.x, f1.w, f2.z};
    float yc[4] = {f0.z, f1.y, f2.x, f2.w};
    float sq[4];
    #pragma unroll
    for (int e = 0; e < 4; ++e)
        sq[e] = fmaf(ya[e], ya[e], fmaf(yb[e], yb[e], yc[e] * yc[e]));

    __syncthreads();

    float acc = 0.0f;
    const float* prow = Pstar + (size_t)rowBase * NN + j0;

    #pragma unroll 4
    for (int r = 0; r < ROWS; ++r) {
        const float4 c  = rowC[r];                                // LDS broadcast
        const float4 p4 = *(const float4*)(prow + (size_t)r * NN); // coalesced 16B
        const float pp[4] = {p4.x, p4.y, p4.z, p4.w};
        #pragma unroll
        for (int e = 0; e < 4; ++e) {
            float d2 = c.x + sq[e];
            d2 = fmaf(c.y, ya[e], d2);
            d2 = fmaf(c.z, yb[e], d2);
            d2 = fmaf(c.w, yc[e], d2);
            d2 = fmaxf(d2, 0.0f);
            const float q  = __builtin_amdgcn_rcpf(1.0f + d2);
            const float p  = fmaxf(pp[e], 1e-12f);  // upper clip is a no-op in fp32
            const float lp = __log2f(p);
            const float lm = __log2f(1.0f - p);
            acc += lm + q * (lp - lm);
        }
    }

    // Wave (64-lane) shuffle reduce, then cross-wave via LDS.
    #pragma unroll
    for (int off = 32; off > 0; off >>= 1)
        acc += __shfl_down(acc, off);
    const int lane = tid & 63;
    const int wid  = tid >> 6;
    if (lane == 0) waveSum[wid] = acc;
    __syncthreads();
    if (tid == 0) {
        const float bp = waveSum[0] + waveSum[1] + waveSum[2] + waveSum[3];
        // scale: -ln2 / N^2  (log2-units -> natural log, negate, mean)
        atomicAdd(out, bp * (-0.69314718055994531f / 67108864.0f));
    }

    // Pass-through output: pred_pos -> out[1..24576]. Disjoint from out[0].
    if (bid < COPYBLKS) {
        const int k = bid * 256 + tid;
        out[1 + k] = pos[k];
    }
}

extern "C" void kernel_launch(void* const* d_in, const int* in_sizes, int n_in,
                              void* d_out, int out_size, void* d_ws, size_t ws_size,
                              hipStream_t stream) {
    const float* Pstar = (const float*)d_in[0];   // [8192*8192] f32
    const float* pos   = (const float*)d_in[1];   // [8192*3]    f32
    float* out = (float*)d_out;                   // [1 + 24576] f32

    // d_out is poisoned before every launch: zero the atomic accumulator.
    hipMemsetAsync(out, 0, sizeof(float), stream);
    bce_tsne_kernel<<<NBLK, 256, 0, stream>>>(Pstar, pos, out);
}